// Round 1
// baseline (481.684 us; speedup 1.0000x reference)
//
#include <hip/hip_runtime.h>

typedef __bf16 bf16_t;
typedef bf16_t bf16x4 __attribute__((ext_vector_type(4)));
typedef bf16_t bf16x8 __attribute__((ext_vector_type(8)));
typedef float  floatx4 __attribute__((ext_vector_type(4)));

constexpr int Mdim = 2048;
constexpr int Kdim = 4096;
constexpr int Ndim = 11008;
constexpr int NPK  = Ndim / 8;   // 1376 packed words per row
constexpr int BM = 128, BN = 128, BK = 32;
constexpr int SA = 40;  // LDS stride (bf16 elems) for A rows: 80 B, 16B-aligned
constexpr int SB = 40;  // LDS stride for B columns

__global__ __launch_bounds__(256, 2)
void qgemm_kernel(const float* __restrict__ x,
                  const unsigned int* __restrict__ qweight,
                  const unsigned int* __restrict__ qzeros,
                  const float* __restrict__ scales,
                  const float* __restrict__ bias,
                  float* __restrict__ out)
{
    __shared__ bf16_t As[BM * SA];          // 10240 B  [m][k]
    __shared__ bf16_t Bs[BN * SB];          // 10240 B  [n][k]
    __shared__ unsigned int qbuf[BK * 16];  //  2048 B  [k][c] raw packed words

    const int t  = threadIdx.x;
    const int m0 = blockIdx.y * BM;
    const int n0 = blockIdx.x * BN;
    const int c0 = n0 >> 3;                 // packed-word column offset

    const int wave = t >> 6;
    const int lane = t & 63;
    const int quad = lane >> 4;
    const int l16  = lane & 15;
    const int mw = (wave >> 1) * 64;
    const int nw = (wave & 1) * 64;

    floatx4 acc[4][4];
#pragma unroll
    for (int i = 0; i < 4; ++i)
#pragma unroll
        for (int j = 0; j < 4; ++j)
            acc[i][j] = (floatx4){0.f, 0.f, 0.f, 0.f};

    // phase-1 staging indices
    const int arow = t >> 3;                // 0..31
    const int acol = (t & 7) * 4;           // 0,4,..,28
    const int qc   = t & 15;                // 0..15
    const int qk   = t >> 4;                // 0..15

    // phase-2 dequant indices: each thread owns one n column, half the k's
    const int nloc  = t & 127;              // 0..127
    const int khalf = t >> 7;               // 0..1
    const int cc    = nloc >> 3;            // which packed word
    const int jsh   = (nloc & 7) * 4;       // nibble shift

    for (int kt = 0; kt < Kdim / BK; ++kt) {
        const int k0 = kt * BK;
        const int g  = k0 >> 7;             // quant group (BK=32 | GS=128)

        // ---- phase 1: stage A (fp32->bf16) + raw qweight words ----
#pragma unroll
        for (int p = 0; p < 4; ++p) {
            const float4 v = *(const float4*)(x + (size_t)(m0 + p * 32 + arow) * Kdim + k0 + acol);
            bf16x4 a4;
            a4[0] = (bf16_t)v.x; a4[1] = (bf16_t)v.y;
            a4[2] = (bf16_t)v.z; a4[3] = (bf16_t)v.w;
            *(bf16x4*)&As[(p * 32 + arow) * SA + acol] = a4;
        }
        qbuf[qk * 16 + qc]        = qweight[(size_t)(k0 + qk) * NPK + c0 + qc];
        qbuf[(qk + 16) * 16 + qc] = qweight[(size_t)(k0 + qk + 16) * NPK + c0 + qc];
        __syncthreads();

        // ---- phase 2: dequant -> Bs[n][k] (contiguous-k b128 writes) ----
        {
            const unsigned zw = qzeros[(size_t)g * NPK + c0 + cc];
            const float s   = scales[(size_t)g * Ndim + n0 + nloc];
            const float zs  = (float)((zw >> jsh) & 15u) * s;
            bf16x8 lo, hi;
#pragma unroll
            for (int kk = 0; kk < 8; ++kk) {
                const unsigned wq = qbuf[(khalf * 16 + kk) * 16 + cc];
                lo[kk] = (bf16_t)((float)((wq >> jsh) & 15u) * s - zs);
            }
#pragma unroll
            for (int kk = 0; kk < 8; ++kk) {
                const unsigned wq = qbuf[(khalf * 16 + 8 + kk) * 16 + cc];
                hi[kk] = (bf16_t)((float)((wq >> jsh) & 15u) * s - zs);
            }
            *(bf16x8*)&Bs[nloc * SB + khalf * 16]     = lo;
            *(bf16x8*)&Bs[nloc * SB + khalf * 16 + 8] = hi;
        }
        __syncthreads();

        // ---- phase 3: MFMA ----
        bf16x8 fa[4], fb[4];
#pragma unroll
        for (int mt = 0; mt < 4; ++mt)
            fa[mt] = *(const bf16x8*)&As[(mw + mt * 16 + l16) * SA + quad * 8];
#pragma unroll
        for (int nt = 0; nt < 4; ++nt)
            fb[nt] = *(const bf16x8*)&Bs[(nw + nt * 16 + l16) * SB + quad * 8];
#pragma unroll
        for (int mt = 0; mt < 4; ++mt)
#pragma unroll
            for (int nt = 0; nt < 4; ++nt)
                acc[mt][nt] = __builtin_amdgcn_mfma_f32_16x16x32_bf16(fa[mt], fb[nt], acc[mt][nt], 0, 0, 0);
        __syncthreads();
    }

    // ---- epilogue: C[row][col] with row=(quad*4+r), col=l16 per 16x16 tile ----
#pragma unroll
    for (int nt = 0; nt < 4; ++nt) {
        const int col = n0 + nw + nt * 16 + l16;
        const float b = bias[col];
#pragma unroll
        for (int mt = 0; mt < 4; ++mt) {
#pragma unroll
            for (int r = 0; r < 4; ++r) {
                const int row = m0 + mw + mt * 16 + quad * 4 + r;
                out[(size_t)row * Ndim + col] = acc[mt][nt][r] + b;
            }
        }
    }
}

extern "C" void kernel_launch(void* const* d_in, const int* in_sizes, int n_in,
                              void* d_out, int out_size, void* d_ws, size_t ws_size,
                              hipStream_t stream)
{
    const float*        x       = (const float*)d_in[0];
    const unsigned int* qweight = (const unsigned int*)d_in[1];
    const unsigned int* qzeros  = (const unsigned int*)d_in[2];
    const float*        scales  = (const float*)d_in[3];
    const float*        bias    = (const float*)d_in[4];
    float*              out     = (float*)d_out;

    dim3 grid(Ndim / BN, Mdim / BM);  // 86 x 16 = 1376 blocks
    qgemm_kernel<<<grid, dim3(256), 0, stream>>>(x, qweight, qzeros, scales, bias, out);
}

// Round 2
// 398.755 us; speedup vs baseline: 1.2080x; 1.2080x over previous
//
#include <hip/hip_runtime.h>

typedef __bf16 bf16_t;
typedef bf16_t bf16x8 __attribute__((ext_vector_type(8)));
typedef float  floatx4 __attribute__((ext_vector_type(4)));
typedef unsigned int uint;

constexpr int Mdim = 2048;
constexpr int Kdim = 4096;
constexpr int Ndim = 11008;
constexpr int NPK  = Ndim / 8;     // 1376 packed words per k-row
constexpr int BM = 128, BN = 128, BK = 64;
constexpr int SA = 72;             // As stride (bf16): 144 B -> (row+o)%8 group spread, 2-way free
constexpr int SB = 72;             // Bs stride (bf16)
constexpr int SQ = 68;             // qbuf stride (words): 272 B, 16B-aligned, (c+i)%8 spread

__global__ void xcast_kernel(const float* __restrict__ x, bf16_t* __restrict__ xb)
{
    const int i = (blockIdx.x * 256 + threadIdx.x) * 8;
    const float4 a = *(const float4*)(x + i);
    const float4 b = *(const float4*)(x + i + 4);
    bf16x8 v;
    v[0] = (bf16_t)a.x; v[1] = (bf16_t)a.y; v[2] = (bf16_t)a.z; v[3] = (bf16_t)a.w;
    v[4] = (bf16_t)b.x; v[5] = (bf16_t)b.y; v[6] = (bf16_t)b.z; v[7] = (bf16_t)b.w;
    *(bf16x8*)(xb + i) = v;
}

template <bool PRE>
__global__ __launch_bounds__(256, 3)
void qgemm_kernel(const float* __restrict__ x,
                  const bf16_t* __restrict__ xb,
                  const uint* __restrict__ qweight,
                  const uint* __restrict__ qzeros,
                  const float* __restrict__ scales,
                  const float* __restrict__ bias,
                  float* __restrict__ out)
{
    __shared__ bf16_t As[BM * SA];   // 18432 B  [m][k]
    __shared__ bf16_t Bs[BN * SB];   // 18432 B  [n][k]
    __shared__ uint   qbuf[16 * SQ]; //  4352 B  [c][k] transposed packed words

    const int t  = threadIdx.x;
    const int m0 = blockIdx.y * BM;
    const int n0 = blockIdx.x * BN;
    const int c0 = n0 >> 3;

    const int wave = t >> 6;
    const int lane = t & 63;
    const int quad = lane >> 4;
    const int l16  = lane & 15;
    const int mw = (wave >> 1) * 64;
    const int nw = (wave & 1) * 64;

    floatx4 acc[4][4];
#pragma unroll
    for (int i = 0; i < 4; ++i)
#pragma unroll
        for (int j = 0; j < 4; ++j)
            acc[i][j] = (floatx4){0.f, 0.f, 0.f, 0.f};

    // A-staging indices: 4 chunks of 16B per thread; chunk = p*256+t -> m=chunk>>3, o=chunk&7
    const int am = t >> 3;          // 0..31 (+32p)
    const int ao = t & 7;           // k-octet
    // qbuf staging: thread loads dwordx4 at (k0 + qk, c0 + qc4..+3), writes transposed
    const int qk  = t >> 2;         // 0..63
    const int qc4 = (t & 3) * 4;
    // dequant: thread owns column nloc, half the k's
    const int nloc  = t & 127;
    const int khalf = t >> 7;
    const int cc    = nloc >> 3;
    const int jsh   = (nloc & 7) * 4;

    for (int kt = 0; kt < Kdim / BK; ++kt) {
        const int k0 = kt * BK;
        const int g  = k0 >> 7;     // quant group (BK=64 divides GS=128)

        // ---- phase 1: stage A (b128 copy) + qweight words (transposed) ----
#pragma unroll
        for (int p = 0; p < 4; ++p) {
            const int m = p * 32 + am;
            if (PRE) {
                const bf16x8 v = *(const bf16x8*)(xb + (size_t)(m0 + m) * Kdim + k0 + ao * 8);
                *(bf16x8*)&As[m * SA + ao * 8] = v;
            } else {
                const float* src = x + (size_t)(m0 + m) * Kdim + k0 + ao * 8;
                const float4 a = *(const float4*)src;
                const float4 b = *(const float4*)(src + 4);
                bf16x8 v;
                v[0] = (bf16_t)a.x; v[1] = (bf16_t)a.y; v[2] = (bf16_t)a.z; v[3] = (bf16_t)a.w;
                v[4] = (bf16_t)b.x; v[5] = (bf16_t)b.y; v[6] = (bf16_t)b.z; v[7] = (bf16_t)b.w;
                *(bf16x8*)&As[m * SA + ao * 8] = v;
            }
        }
        {
            const uint4 w4 = *(const uint4*)(qweight + (size_t)(k0 + qk) * NPK + c0 + qc4);
            qbuf[(qc4 + 0) * SQ + qk] = w4.x;
            qbuf[(qc4 + 1) * SQ + qk] = w4.y;
            qbuf[(qc4 + 2) * SQ + qk] = w4.z;
            qbuf[(qc4 + 3) * SQ + qk] = w4.w;
        }
        __syncthreads();

        // ---- phase 2: dequant -> Bs[n][k] (b128 reads from qbuf, b128 writes) ----
        {
            const uint  zw = qzeros[(size_t)g * NPK + c0 + cc];
            const float s  = scales[(size_t)g * Ndim + n0 + nloc];
            const float zs = (float)((zw >> jsh) & 15u) * s;
            const uint* qrow = &qbuf[cc * SQ + khalf * 32];
#pragma unroll
            for (int j = 0; j < 4; ++j) {
                const uint4 qa = *(const uint4*)(qrow + j * 8);
                const uint4 qb = *(const uint4*)(qrow + j * 8 + 4);
                bf16x8 v;
                v[0] = (bf16_t)((float)((qa.x >> jsh) & 15u) * s - zs);
                v[1] = (bf16_t)((float)((qa.y >> jsh) & 15u) * s - zs);
                v[2] = (bf16_t)((float)((qa.z >> jsh) & 15u) * s - zs);
                v[3] = (bf16_t)((float)((qa.w >> jsh) & 15u) * s - zs);
                v[4] = (bf16_t)((float)((qb.x >> jsh) & 15u) * s - zs);
                v[5] = (bf16_t)((float)((qb.y >> jsh) & 15u) * s - zs);
                v[6] = (bf16_t)((float)((qb.z >> jsh) & 15u) * s - zs);
                v[7] = (bf16_t)((float)((qb.w >> jsh) & 15u) * s - zs);
                *(bf16x8*)&Bs[nloc * SB + khalf * 32 + j * 8] = v;
            }
        }
        __syncthreads();

        // ---- phase 3: MFMA, 2 k-steps of 32 ----
#pragma unroll
        for (int s = 0; s < 2; ++s) {
            bf16x8 fa[4], fb[4];
#pragma unroll
            for (int mt = 0; mt < 4; ++mt)
                fa[mt] = *(const bf16x8*)&As[(mw + mt * 16 + l16) * SA + s * 32 + quad * 8];
#pragma unroll
            for (int nt = 0; nt < 4; ++nt)
                fb[nt] = *(const bf16x8*)&Bs[(nw + nt * 16 + l16) * SB + s * 32 + quad * 8];
#pragma unroll
            for (int mt = 0; mt < 4; ++mt)
#pragma unroll
                for (int nt = 0; nt < 4; ++nt)
                    acc[mt][nt] = __builtin_amdgcn_mfma_f32_16x16x32_bf16(fa[mt], fb[nt], acc[mt][nt], 0, 0, 0);
        }
        __syncthreads();
    }

    // ---- epilogue: row=(quad*4+r), col=l16 per 16x16 tile (verified round 1) ----
#pragma unroll
    for (int nt = 0; nt < 4; ++nt) {
        const int col = n0 + nw + nt * 16 + l16;
        const float b = bias[col];
#pragma unroll
        for (int mt = 0; mt < 4; ++mt) {
#pragma unroll
            for (int r = 0; r < 4; ++r) {
                const int row = m0 + mw + mt * 16 + quad * 4 + r;
                out[(size_t)row * Ndim + col] = acc[mt][nt][r] + b;
            }
        }
    }
}

extern "C" void kernel_launch(void* const* d_in, const int* in_sizes, int n_in,
                              void* d_out, int out_size, void* d_ws, size_t ws_size,
                              hipStream_t stream)
{
    const float* x        = (const float*)d_in[0];
    const uint*  qweight  = (const uint*)d_in[1];
    const uint*  qzeros   = (const uint*)d_in[2];
    const float* scales   = (const float*)d_in[3];
    const float* bias     = (const float*)d_in[4];
    float*       out      = (float*)d_out;
    bf16_t*      xb       = (bf16_t*)d_ws;

    const size_t xb_bytes = (size_t)Mdim * Kdim * sizeof(bf16_t);
    dim3 grid(Ndim / BN, Mdim / BM);   // 86 x 16 = 1376 blocks

    if (ws_size >= xb_bytes) {
        xcast_kernel<<<(Mdim * Kdim) / (256 * 8), 256, 0, stream>>>(x, xb);
        qgemm_kernel<true><<<grid, dim3(256), 0, stream>>>(x, xb, qweight, qzeros, scales, bias, out);
    } else {
        qgemm_kernel<false><<<grid, dim3(256), 0, stream>>>(x, xb, qweight, qzeros, scales, bias, out);
    }
}